// Round 11
// baseline (4862.141 us; speedup 1.0000x reference)
//
#include <hip/hip_runtime.h>

// Fused tanh-RNN: y[b,t] = W_fc . h[b,t] + b_fc,  h_t = tanh(x_t W_ih^T + b_ih + b_hh + h_{t-1} W_hh^T)
// B=2048, S=512, I=40, H=64.
//
// One 64-lane wave per block, one block per batch element (2048 blocks ->
// 8 blocks/CU = 2 waves/SIMD, perfectly balanced). Lane j owns hidden unit j.
// POST-MORTEM OF r5 (579us, VALUBusy 49%, ~330 VALU instrs/step vs ~130
// modeled) baked into this design:
//  - f32x2/v_pk_fma formulation scalarized with heavy v_mov marshalling
//    -> plain scalar fmaf (104 FMA/step, 2cy each, SIMD-32).
//  - uniform-address GLOBAL x reads thrashed L1 (8 blocks x 5KB > 32KB)
//    and 40 long-lived touch regs squeezed VGPR to 128 (56MB anomalous
//    WRITE_SIZE = scratch spills) -> LDS double-buffered x staging;
//    broadcast ds_read_b128 costs ~2cy of the 256B/cy DS pipe, not 12.
//  - batched-head gs reads: 32 rows x b128 on 8 bank-quad-groups => 4-way
//    is the conflict floor; GPAD 68 (odd/4 stride) achieves it AND keeps
//    total LDS at 19456 B/block -> 8 blocks/CU = 152 KiB < 160 KiB pool
//    (GPAD 76 was 20480 B -> 8 blocks landed on EXACTLY 160 KiB; any
//    runtime LDS reserve would silently drop occupancy to 7 + tail).
// Kept (sound):
//  - xw pre-pass: input projection for 32 staged steps into 32 VGPRs with
//    full ILP, off the serial chain.
//  - batched head: per step gs[s][lane] = h*wfc (1 mul + 1 ds_write); block-
//    end row-sum + one shfl_xor(32); no per-step 6-deep shuffle chain.
//  - h via wave-private LDS ping-pong, zero barriers (single-wave blocks).
// All loops fully unrolled -> compile-time indices only (no scratch).

#define RNN_B 2048
#define RNN_S 512
#define RNN_I 40
#define RNN_H 64
#define TBLK  32                  // timesteps per staging block
#define TFLT  (TBLK * RNN_I)      // 1280 floats per stage buffer
#define GPAD  68                  // gs row stride (16B-aligned, 4-way floor)

__device__ __forceinline__ float fast_tanh(float p) {
    // tanh(p) = 1 - 2/(e^{2p}+1). Saturation-safe: exp->inf => 1, exp->0 => -1.
#if __has_builtin(__builtin_amdgcn_exp2f)
    const float e = __builtin_amdgcn_exp2f(p * 2.885390081777927f); // 2*log2(e)
#else
    const float e = __expf(2.f * p);
#endif
    return 1.f - __fdividef(2.f, e + 1.f);
}

__global__ __launch_bounds__(64, 2)
void rnn_fused(const float* __restrict__ x,
               const float* __restrict__ W_ih,
               const float* __restrict__ W_hh,
               const float* __restrict__ b_ih,
               const float* __restrict__ b_hh,
               const float* __restrict__ W_fc,
               const float* __restrict__ b_fc,
               float* __restrict__ out)
{
    const int lane = threadIdx.x & 63;
    const int b    = blockIdx.x;

    __shared__ float xs[2][TFLT];       // double-buffered x stage
    __shared__ float hs[2][RNN_H];      // ping-pong hidden state
    __shared__ float gs[TBLK][GPAD];    // per-step h*wfc, for batched head

    // Per-lane weight rows -> scalar registers (one-time, cached loads).
    float wih[RNN_I];
#pragma unroll
    for (int k = 0; k < RNN_I; ++k) wih[k] = W_ih[lane * RNN_I + k];
    float whh[RNN_H];
#pragma unroll
    for (int k = 0; k < RNN_H; ++k) whh[k] = W_hh[lane * RNN_H + k];
    const float bias = b_ih[lane] + b_hh[lane];
    const float wfc  = W_fc[lane];
    const float bfc  = b_fc[0];

    hs[0][lane] = 0.f;   // h0 = 0

    const float* __restrict__ xrow = x + (size_t)b * (RNN_S * RNN_I);
    float* __restrict__ orow       = out + (size_t)b * RNN_S;

    // Stage block 0: 1280 consecutive floats, 16 B/lane coalesced.
#pragma unroll
    for (int i = 0; i < TFLT / 256; ++i)
        *(float4*)&xs[0][256 * i + 4 * lane] =
            *(const float4*)&xrow[256 * i + 4 * lane];

    for (int T = 0; T < RNN_S; T += TBLK) {
        const int  buf  = (T >> 5) & 1;
        const bool more = (T + TBLK) < RNN_S;

        // Issue next block's global loads now; landed after the pre-pass.
        float4 xn[TFLT / 256];
        if (more) {
#pragma unroll
            for (int i = 0; i < TFLT / 256; ++i)
                xn[i] = *(const float4*)&xrow[(T + TBLK) * RNN_I + 256 * i + 4 * lane];
        }

        // ---- xw pre-pass: input projection for all 32 staged steps, full ILP.
        // 10 broadcast ds_read_b128 + 40 scalar fmaf per step; no serial dep.
        float xw[TBLK];
#pragma unroll
        for (int s = 0; s < TBLK; ++s) {
            float a0 = bias, a1 = 0.f, a2 = 0.f, a3 = 0.f;
#pragma unroll
            for (int k4 = 0; k4 < RNN_I / 4; ++k4) {
                const float4 xv = *(const float4*)&xs[buf][s * RNN_I + 4 * k4];
                a0 = fmaf(xv.x, wih[4 * k4 + 0], a0);
                a1 = fmaf(xv.y, wih[4 * k4 + 1], a1);
                a2 = fmaf(xv.z, wih[4 * k4 + 2], a2);
                a3 = fmaf(xv.w, wih[4 * k4 + 3], a3);
            }
            xw[s] = (a0 + a1) + (a2 + a3);
        }

        // ---- land the prefetched next x block (xs[buf] fully consumed).
        if (more) {
#pragma unroll
            for (int i = 0; i < TFLT / 256; ++i)
                *(float4*)&xs[buf ^ 1][256 * i + 4 * lane] = xn[i];
        }

        // ---- serial recurrent phase: 32 steps, fully unrolled, no shuffles.
#pragma unroll
        for (int s = 0; s < TBLK; ++s) {
            const int hc = s & 1;

            float a0 = xw[s], a1 = 0.f, a2 = 0.f, a3 = 0.f;
#pragma unroll
            for (int q = 0; q < RNN_H / 16; ++q) {
                const float4 h0 = *(const float4*)&hs[hc][16 * q];
                const float4 h1 = *(const float4*)&hs[hc][16 * q + 4];
                const float4 h2 = *(const float4*)&hs[hc][16 * q + 8];
                const float4 h3 = *(const float4*)&hs[hc][16 * q + 12];
                a0 = fmaf(h0.x, whh[16 * q + 0], a0);
                a1 = fmaf(h0.y, whh[16 * q + 1], a1);
                a2 = fmaf(h0.z, whh[16 * q + 2], a2);
                a3 = fmaf(h0.w, whh[16 * q + 3], a3);
                a0 = fmaf(h1.x, whh[16 * q + 4], a0);
                a1 = fmaf(h1.y, whh[16 * q + 5], a1);
                a2 = fmaf(h1.z, whh[16 * q + 6], a2);
                a3 = fmaf(h1.w, whh[16 * q + 7], a3);
                a0 = fmaf(h2.x, whh[16 * q + 8], a0);
                a1 = fmaf(h2.y, whh[16 * q + 9], a1);
                a2 = fmaf(h2.z, whh[16 * q + 10], a2);
                a3 = fmaf(h2.w, whh[16 * q + 11], a3);
                a0 = fmaf(h3.x, whh[16 * q + 12], a0);
                a1 = fmaf(h3.y, whh[16 * q + 13], a1);
                a2 = fmaf(h3.z, whh[16 * q + 14], a2);
                a3 = fmaf(h3.w, whh[16 * q + 15], a3);
            }
            const float pre = (a0 + a1) + (a2 + a3);

            const float h = fast_tanh(pre);
            hs[hc ^ 1][lane] = h;       // next step's input
            gs[s][lane]      = h * wfc; // head contribution, reduced below
        }

        // ---- batched head: out[T+r] = sum_k gs[r][k] + bfc.
        // Lane l sums row (l&31), cols [32*(l>>5), +32); halves combined
        // with one shfl_xor(32); lanes 0..31 store 128 B coalesced.
        {
            const int r    = lane & 31;
            const int half = lane >> 5;
            float p0 = 0.f, p1 = 0.f, p2 = 0.f, p3 = 0.f;
#pragma unroll
            for (int c = 0; c < 8; ++c) {
                const float4 v = *(const float4*)&gs[r][32 * half + 4 * c];
                p0 += v.x; p1 += v.y; p2 += v.z; p3 += v.w;
            }
            float p = (p0 + p1) + (p2 + p3);
            p += __shfl_xor(p, 32, 64);
            if (half == 0) orow[T + r] = p + bfc;
        }
    }
}

extern "C" void kernel_launch(void* const* d_in, const int* in_sizes, int n_in,
                              void* d_out, int out_size, void* d_ws, size_t ws_size,
                              hipStream_t stream) {
    const float* x    = (const float*)d_in[0];
    const float* W_ih = (const float*)d_in[1];
    const float* W_hh = (const float*)d_in[2];
    const float* b_ih = (const float*)d_in[3];
    const float* b_hh = (const float*)d_in[4];
    const float* W_fc = (const float*)d_in[5];
    const float* b_fc = (const float*)d_in[6];
    float* out = (float*)d_out;

    dim3 grid(RNN_B);
    dim3 block(64);
    hipLaunchKernelGGL(rnn_fused, grid, block, 0, stream,
                       x, W_ih, W_hh, b_ih, b_hh, W_fc, b_fc, out);
}